// Round 8
// baseline (48.650 us; speedup 1.0000x reference)
//
#include <hip/hip_runtime.h>
#include <math.h>

#define BLOCK 256

// 16-lane-row sum-reduce via DPP row_ror (VALU-only, no DS pipe, no lgkmcnt).
// After ror:1,2,4,8 every lane of each 16-lane row holds the row's full sum.
template <int CTRL>
__device__ __forceinline__ float dpp_ror_add(float x) {
    const int r = __builtin_amdgcn_update_dpp(0, __float_as_int(x), CTRL, 0xF, 0xF, true);
    return x + __int_as_float(r);
}
__device__ __forceinline__ float row16_sum(float p) {
    p = dpp_ror_add<0x121>(p);   // row_ror:1
    p = dpp_ror_add<0x122>(p);   // row_ror:2
    p = dpp_ror_add<0x124>(p);   // row_ror:4
    p = dpp_ror_add<0x128>(p);   // row_ror:8
    return p;
}

// Single fused kernel: 4 segments per block (2 pairs), 2 waves per pair.
// Each block computes its own offset prefix directly from slices (32 KB,
// L2-broadcast-hot across blocks) -- no helper kernel, no launch gap.
__global__ __launch_bounds__(BLOCK, 8) void attn_pool_fused(
    const float* __restrict__ x, const int* __restrict__ slices,
    const float* __restrict__ W, const float* __restrict__ bias,
    float* __restrict__ out, int S) {
    __shared__ int    wred[4];
    __shared__ float4 combA[2][2][2][16];   // [pairInBlk][waveInPair][seg][col4]
    __shared__ float  combD[2][2][2];

    const int tid  = threadIdx.x;
    const int lane = tid & 63;
    const int wave = tid >> 6;
    const int s0   = blockIdx.x << 2;       // first of this block's 4 segments

    // ---- block-wide prefix: sum(slices[0..s0)); s0 % 4 == 0 -> exact int4s ----
    int part = 0;
    {
        const int cnt4 = s0 >> 2;
        const int4* __restrict__ sl4 = (const int4*)slices;
        for (int i = tid; i < cnt4; i += BLOCK) {
            const int4 v = sl4[i];
            part += v.x + v.y + v.z + v.w;
        }
#pragma unroll
        for (int m = 1; m < 64; m <<= 1) part += __shfl_xor(part, m, 64);
        if (lane == 0) wred[wave] = part;
    }
    __syncthreads();
    const size_t P = (size_t)(wred[0] + wred[1] + wred[2] + wred[3]);

    // this block's 4 segment lengths
    const int n0 = (s0     < S) ? slices[s0]     : 0;
    const int n1 = (s0 + 1 < S) ? slices[s0 + 1] : 0;
    const int n2 = (s0 + 2 < S) ? slices[s0 + 2] : 0;
    const int n3 = (s0 + 3 < S) ? slices[s0 + 3] : 0;

    const int pi = wave >> 1;               // pair in block (0..1)
    const int w  = wave & 1;                // wave in pair  (0..1)
    const int nA = pi ? n2 : n0;
    const int nB = pi ? n3 : n1;
    const size_t offA = pi ? (P + (size_t)(n0 + n1)) : P;

    const int grp = lane >> 4;
    const int c0  = (lane & 15) << 2;
    const float w0 = W[1 + c0 + 0];
    const float w1 = W[1 + c0 + 1];
    const float w2 = W[1 + c0 + 2];
    const float w3 = W[1 + c0 + 3];
    const float Wpos = W[0];
    // bias[0] shifts all logits of a segment equally -> cancels in softmax.

    float4 acc0 = make_float4(0.f, 0.f, 0.f, 0.f);
    float4 acc1 = make_float4(0.f, 0.f, 0.f, 0.f);
    float den0 = 0.f, den1 = 0.f;

    const int K0 = (nA + 3) >> 2;
    const int K1 = (nB + 3) >> 2;
    const int T  = K0 + K1;
    const int half = (T + 1) >> 1;
    const int t0 = w * half;
    const int t1 = min(T, t0 + half);

    const float psA = nA ? (Wpos / (float)nA) : 0.f;
    const float psB = nB ? (Wpos / (float)nB) : 0.f;

    const float4* __restrict__ baseA = (const float4*)x + offA * 16 + lane;
    const float4* __restrict__ baseB = baseA + (size_t)nA * 16;

    // seg A portion of this wave's chunk range
    const int ea = min(t1, K0);
#pragma unroll 4
    for (int t = t0; t < ea; ++t) {
        const int r = (t << 2) + grp;
        if (r < nA) {
            const float4 v = baseA[(size_t)t << 6];
            float p = fmaf(v.x, w0, fmaf(v.y, w1, fmaf(v.z, w2, v.w * w3)));
            p = row16_sum(p);               // VALU DPP reduce over the 16-lane row
            const float e = __expf(fmaf((float)r, psA, p));
            acc0.x = fmaf(e, v.x, acc0.x);
            acc0.y = fmaf(e, v.y, acc0.y);
            acc0.z = fmaf(e, v.z, acc0.z);
            acc0.w = fmaf(e, v.w, acc0.w);
            den0 += e;
        }
    }
    // seg B portion
    const int bb = max(t0, K0);
#pragma unroll 4
    for (int t = bb; t < t1; ++t) {
        const int k = t - K0;
        const int r = (k << 2) + grp;
        if (r < nB) {
            const float4 v = baseB[(size_t)k << 6];
            float p = fmaf(v.x, w0, fmaf(v.y, w1, fmaf(v.z, w2, v.w * w3)));
            p = row16_sum(p);
            const float e = __expf(fmaf((float)r, psB, p));
            acc1.x = fmaf(e, v.x, acc1.x);
            acc1.y = fmaf(e, v.y, acc1.y);
            acc1.z = fmaf(e, v.z, acc1.z);
            acc1.w = fmaf(e, v.w, acc1.w);
            den1 += e;
        }
    }

    // merge the 4 row-groups (disjoint rows; within a group all 16 lanes hold
    // identical den partials -> group-merge ONLY, never a full butterfly)
#pragma unroll
    for (int m = 16; m < 64; m <<= 1) {
        acc0.x += __shfl_xor(acc0.x, m, 64);
        acc0.y += __shfl_xor(acc0.y, m, 64);
        acc0.z += __shfl_xor(acc0.z, m, 64);
        acc0.w += __shfl_xor(acc0.w, m, 64);
        acc1.x += __shfl_xor(acc1.x, m, 64);
        acc1.y += __shfl_xor(acc1.y, m, 64);
        acc1.z += __shfl_xor(acc1.z, m, 64);
        acc1.w += __shfl_xor(acc1.w, m, 64);
        den0   += __shfl_xor(den0,   m, 64);
        den1   += __shfl_xor(den1,   m, 64);
    }

    if (lane < 16) {
        combA[pi][w][0][lane] = acc0;
        combA[pi][w][1][lane] = acc1;
    }
    if (lane == 0) {
        combD[pi][w][0] = den0;
        combD[pi][w][1] = den1;
    }
    __syncthreads();

    // each wave writes one (pair, seg) output
    const int po   = wave >> 1;
    const int seg  = wave & 1;
    const int sOut = s0 + (po << 1) + seg;
    if (sOut < S && lane < 16) {
        const float4 a0 = combA[po][0][seg][lane];
        const float4 a1 = combA[po][1][seg][lane];
        const float inv = 1.f / (combD[po][0][seg] + combD[po][1][seg]);
        float4 r4;
        r4.x = (a0.x + a1.x) * inv;
        r4.y = (a0.y + a1.y) * inv;
        r4.z = (a0.z + a1.z) * inv;
        r4.w = (a0.w + a1.w) * inv;
        ((float4*)out)[(size_t)sOut * 16 + lane] = r4;
    }
}

extern "C" void kernel_launch(void* const* d_in, const int* in_sizes, int n_in,
                              void* d_out, int out_size, void* d_ws, size_t ws_size,
                              hipStream_t stream) {
    const float* x      = (const float*)d_in[0];
    const int*   slices = (const int*)d_in[1];
    const float* W      = (const float*)d_in[2];
    const float* bias   = (const float*)d_in[3];
    float*       out    = (float*)d_out;
    const int S = in_sizes[1];

    const int grid = (S + 3) >> 2;          // 4 segments per block
    attn_pool_fused<<<grid, BLOCK, 0, stream>>>(x, slices, W, bias, out, S);
}